// Round 2
// baseline (293.865 us; speedup 1.0000x reference)
//
#include <hip/hip_runtime.h>
#include <hip/hip_bf16.h>

typedef __bf16 bf16x8 __attribute__((ext_vector_type(8)));
typedef float f32x4 __attribute__((ext_vector_type(4)));

#define NROW 3072
#define NF 512            // IN_F == H*D == 512
#define NH 8
#define ND 64

// ---------------------------------------------------------------------------
// Kernel 0: dtype sniff. If x's bytes, viewed as bf16, contain inf/nan/denormal
// patterns, the buffer is really fp32 (mode=1). Genuine bf16 N(0,1) never does.
// ---------------------------------------------------------------------------
__global__ __launch_bounds__(256) void k_sniff(const unsigned short* __restrict__ xb,
                                               int* __restrict__ mode) {
    __shared__ int s;
    if (threadIdx.x == 0) s = 0;
    __syncthreads();
    int f = 0;
    for (int i = threadIdx.x; i < 16384; i += 256) {
        unsigned v = xb[i];
        unsigned e = (v >> 7) & 0xFF;
        if (e == 0xFF || (e == 0 && (v & 0x7F))) f = 1;
    }
    if (f) atomicOr(&s, 1);
    __syncthreads();
    if (threadIdx.x == 0) *mode = s;
}

// ---------------------------------------------------------------------------
// Kernel 0b: convert all four float tensors to bf16 in ws (from fp32 or bf16).
// Segments: x (1572864), W (262144), a_src (512), a_dst (512), concatenated.
// ---------------------------------------------------------------------------
__global__ __launch_bounds__(256) void k_convert(const void* __restrict__ s0,
                                                 const void* __restrict__ s1,
                                                 const void* __restrict__ s2,
                                                 const void* __restrict__ s3,
                                                 __bf16* __restrict__ d0,
                                                 __bf16* __restrict__ d1,
                                                 __bf16* __restrict__ d2,
                                                 __bf16* __restrict__ d3,
                                                 const int* __restrict__ mode) {
    const int n0 = NROW * NF, n1 = NF * NF, n2 = NH * ND, n3 = NH * ND;
    int total = n0 + n1 + n2 + n3;
    int fp32 = *mode;
    for (int i = blockIdx.x * 256 + threadIdx.x; i < total; i += gridDim.x * 256) {
        const void* s; __bf16* d; int k = i;
        if (k < n0)            { s = s0; d = d0; }
        else if ((k -= n0) < n1) { s = s1; d = d1; }
        else if ((k -= n1) < n2) { s = s2; d = d2; }
        else { k -= n2;          s = s3; d = d3; }
        if (fp32) d[k] = (__bf16)(((const float*)s)[k]);
        else      d[k] = ((const __bf16*)s)[k];
    }
}

// ---------------------------------------------------------------------------
// Kernel 1: h = x @ W^T (both K-major), write h and hT (per-head d-major).
// ---------------------------------------------------------------------------
__global__ __launch_bounds__(256) void k_gemm_h(const __bf16* __restrict__ x,
                                                const __bf16* __restrict__ W,
                                                __bf16* __restrict__ h,
                                                __bf16* __restrict__ hT) {
    int wave = threadIdx.x >> 6;
    int lane = threadIdx.x & 63;
    int t = blockIdx.x * 4 + wave;          // 6144 tiles: 192 i-tiles x 32 o-tiles
    int i0 = (t >> 5) << 4;
    int o0 = (t & 31) << 4;
    int fr = lane & 15;
    int quad = lane >> 4;

    const bf16x8* xa = reinterpret_cast<const bf16x8*>(x + (i0 + fr) * NF + quad * 8);
    const bf16x8* wb = reinterpret_cast<const bf16x8*>(W + (o0 + fr) * NF + quad * 8);

    f32x4 acc = {0.f, 0.f, 0.f, 0.f};
#pragma unroll
    for (int k = 0; k < 16; ++k) {
        bf16x8 a = xa[k * 4];
        bf16x8 b = wb[k * 4];
        acc = __builtin_amdgcn_mfma_f32_16x16x32_bf16(a, b, acc, 0, 0, 0);
    }
#pragma unroll
    for (int r = 0; r < 4; ++r) {
        int mi = i0 + quad * 4 + r;
        int oo = o0 + fr;
        __bf16 v = (__bf16)acc[r];
        h[mi * NF + oo] = v;
        hT[oo * NROW + mi] = v;
    }
}

// ---------------------------------------------------------------------------
// Kernel 2: e_src[n,h] = <h[n,h,:], a_src[h,:]>, e_dst likewise. fp32 out.
// ---------------------------------------------------------------------------
__global__ __launch_bounds__(64) void k_edges(const __bf16* __restrict__ h,
                                              const __bf16* __restrict__ a_src,
                                              const __bf16* __restrict__ a_dst,
                                              float* __restrict__ e_src,
                                              float* __restrict__ e_dst) {
    int n = blockIdx.x;
    int lane = threadIdx.x;
    bf16x8 hv = *reinterpret_cast<const bf16x8*>(h + n * NF + lane * 8);
    bf16x8 as = *reinterpret_cast<const bf16x8*>(a_src + lane * 8);
    bf16x8 ad = *reinterpret_cast<const bf16x8*>(a_dst + lane * 8);
    float ps = 0.f, pd = 0.f;
#pragma unroll
    for (int t = 0; t < 8; ++t) {
        float hh = (float)hv[t];
        ps += hh * (float)as[t];
        pd += hh * (float)ad[t];
    }
#pragma unroll
    for (int off = 1; off < 8; off <<= 1) {
        ps += __shfl_xor(ps, off, 64);
        pd += __shfl_xor(pd, off, 64);
    }
    if ((lane & 7) == 0) {
        int head = lane >> 3;
        e_src[n * NH + head] = ps;
        e_dst[n * NH + head] = pd;
    }
}

// ---------------------------------------------------------------------------
// Kernel 3: m[i,h] = lrelu(e_src[i,h] + max_{valid j} e_dst[j,h])
// (lrelu monotonic => max commutes with it)
// ---------------------------------------------------------------------------
__global__ __launch_bounds__(256) void k_rowmax(const int* __restrict__ adj,
                                                const float* __restrict__ e_src,
                                                const float* __restrict__ e_dst,
                                                float* __restrict__ m_arr) {
    int i = blockIdx.x;
    int tid = threadIdx.x;
    float mx[NH];
#pragma unroll
    for (int hh = 0; hh < NH; ++hh) mx[hh] = -3e38f;

    for (int j = tid; j < NROW; j += 256) {
        int a = adj[i * NROW + j];
        if (a > 0 || j == i) {
            const float4* ep = reinterpret_cast<const float4*>(e_dst + j * NH);
            float4 e0 = ep[0], e1 = ep[1];
            mx[0] = fmaxf(mx[0], e0.x); mx[1] = fmaxf(mx[1], e0.y);
            mx[2] = fmaxf(mx[2], e0.z); mx[3] = fmaxf(mx[3], e0.w);
            mx[4] = fmaxf(mx[4], e1.x); mx[5] = fmaxf(mx[5], e1.y);
            mx[6] = fmaxf(mx[6], e1.z); mx[7] = fmaxf(mx[7], e1.w);
        }
    }
#pragma unroll
    for (int off = 1; off < 64; off <<= 1) {
#pragma unroll
        for (int hh = 0; hh < NH; ++hh) mx[hh] = fmaxf(mx[hh], __shfl_xor(mx[hh], off, 64));
    }
    __shared__ float red[4][NH];
    if ((tid & 63) == 0) {
#pragma unroll
        for (int hh = 0; hh < NH; ++hh) red[tid >> 6][hh] = mx[hh];
    }
    __syncthreads();
    if (tid < NH) {
        float v = fmaxf(fmaxf(red[0][tid], red[1][tid]), fmaxf(red[2][tid], red[3][tid]));
        float e = e_src[i * NH + tid] + v;
        m_arr[i * NH + tid] = e > 0.f ? e : 0.2f * e;
    }
}

// ---------------------------------------------------------------------------
// Kernel 4: flash-style masked softmax-PV.
// Grid: 48 i-blocks (64 rows) x 8 heads = 384 blocks, 256 threads (4 waves).
// Each wave: 16 rows x full d=64 for one head (4 MFMA d-tiles).
// ---------------------------------------------------------------------------
__global__ __launch_bounds__(256) void k_attn(const int* __restrict__ adj,
                                              const float* __restrict__ e_src,
                                              const float* __restrict__ e_dst,
                                              const float* __restrict__ m_arr,
                                              const __bf16* __restrict__ hT,
                                              void* __restrict__ out,
                                              const int* __restrict__ mode) {
    __shared__ float lds_ed[NROW];
    int head = blockIdx.x & 7;
    int i0 = (blockIdx.x >> 3) * 64;
    int tid = threadIdx.x;
    int wave = tid >> 6, lane = tid & 63;
    int fr = lane & 15, quad = lane >> 4;

    for (int j = tid; j < NROW; j += 256) lds_ed[j] = e_dst[j * NH + head];
    __syncthreads();

    int irow = i0 + wave * 16 + fr;
    float s_i = e_src[irow * NH + head];
    float m_i = m_arr[irow * NH + head];
    const int* adjrow = adj + irow * NROW + quad * 8;
    const __bf16* hTh = hT + head * ND * NROW;

    f32x4 acc0 = {0,0,0,0}, acc1 = {0,0,0,0}, acc2 = {0,0,0,0}, acc3 = {0,0,0,0};
    float lsum = 0.f;

    for (int j0 = 0; j0 < NROW; j0 += 32) {
        int4 a0 = *reinterpret_cast<const int4*>(adjrow + j0);
        int4 a1 = *reinterpret_cast<const int4*>(adjrow + j0 + 4);
        int av[8] = {a0.x, a0.y, a0.z, a0.w, a1.x, a1.y, a1.z, a1.w};
        bf16x8 af;
#pragma unroll
        for (int t = 0; t < 8; ++t) {
            int j = j0 + quad * 8 + t;
            float e = s_i + lds_ed[j];
            e = e > 0.f ? e : 0.2f * e;
            // valid j: e - m_i <= 0 by construction; clamp kills overflow/NaN risk
            float p = (av[t] > 0 || j == irow) ? __expf(fminf(e - m_i, 0.f)) : 0.f;
            af[t] = (__bf16)p;
            lsum += (float)af[t];          // denominator consistent with bf16 P
        }
        const __bf16* vb = hTh + fr * NROW + j0 + quad * 8;
        acc0 = __builtin_amdgcn_mfma_f32_16x16x32_bf16(af, *reinterpret_cast<const bf16x8*>(vb),             acc0, 0, 0, 0);
        acc1 = __builtin_amdgcn_mfma_f32_16x16x32_bf16(af, *reinterpret_cast<const bf16x8*>(vb + 16 * NROW), acc1, 0, 0, 0);
        acc2 = __builtin_amdgcn_mfma_f32_16x16x32_bf16(af, *reinterpret_cast<const bf16x8*>(vb + 32 * NROW), acc2, 0, 0, 0);
        acc3 = __builtin_amdgcn_mfma_f32_16x16x32_bf16(af, *reinterpret_cast<const bf16x8*>(vb + 48 * NROW), acc3, 0, 0, 0);
    }

    lsum += __shfl_xor(lsum, 16, 64);
    lsum += __shfl_xor(lsum, 32, 64);    // lane L holds total for row (L&15)

    int fp32out = *mode;
#pragma unroll
    for (int r = 0; r < 4; ++r) {
        int orow = quad * 4 + r;
        float l = __shfl(lsum, orow, 64);
        float inv = 1.0f / fmaxf(l, 1e-30f);
        int ob = (i0 + wave * 16 + orow) * NF + head * ND + fr;
        float v0 = acc0[r] * inv, v1 = acc1[r] * inv, v2 = acc2[r] * inv, v3 = acc3[r] * inv;
        if (fp32out) {
            float* o = (float*)out;
            o[ob] = v0; o[ob + 16] = v1; o[ob + 32] = v2; o[ob + 48] = v3;
        } else {
            __bf16* o = (__bf16*)out;
            o[ob] = (__bf16)v0; o[ob + 16] = (__bf16)v1; o[ob + 32] = (__bf16)v2; o[ob + 48] = (__bf16)v3;
        }
    }
}

// ---------------------------------------------------------------------------
extern "C" void kernel_launch(void* const* d_in, const int* in_sizes, int n_in,
                              void* d_out, int out_size, void* d_ws, size_t ws_size,
                              hipStream_t stream) {
    const void* x_raw  = d_in[0];
    const int*  adj    = (const int*)d_in[1];
    const void* W_raw  = d_in[2];
    const void* as_raw = d_in[3];
    const void* ad_raw = d_in[4];

    char* ws = (char*)d_ws;
    __bf16* h      = (__bf16*)(ws);                      // 3,145,728 B
    __bf16* hT     = (__bf16*)(ws + 3145728);            // 3,145,728 B
    float*  e_src  = (float*)(ws + 6291456);             //    98,304 B
    float*  e_dst  = (float*)(ws + 6389760);             //    98,304 B
    float*  m_arr  = (float*)(ws + 6488064);             //    98,304 B
    int*    mode   = (int*)(ws + 6586368);               //        64 B
    __bf16* xb     = (__bf16*)(ws + 6586432);            // 3,145,728 B
    __bf16* Wb     = (__bf16*)(ws + 9732160);            //   524,288 B
    __bf16* a_srcb = (__bf16*)(ws + 10256448);           //     1,024 B
    __bf16* a_dstb = (__bf16*)(ws + 10257472);           //     1,024 B

    k_sniff<<<1, 256, 0, stream>>>((const unsigned short*)x_raw, mode);
    k_convert<<<1024, 256, 0, stream>>>(x_raw, W_raw, as_raw, ad_raw,
                                        xb, Wb, a_srcb, a_dstb, mode);
    k_gemm_h<<<1536, 256, 0, stream>>>(xb, Wb, h, hT);
    k_edges<<<NROW, 64, 0, stream>>>(h, a_srcb, a_dstb, e_src, e_dst);
    k_rowmax<<<NROW, 256, 0, stream>>>(adj, e_src, e_dst, m_arr);
    k_attn<<<384, 256, 0, stream>>>(adj, e_src, e_dst, m_arr, hT, d_out, mode);
}

// Round 3
// 241.004 us; speedup vs baseline: 1.2193x; 1.2193x over previous
//
#include <hip/hip_runtime.h>
#include <hip/hip_bf16.h>

typedef __bf16 bf16x8 __attribute__((ext_vector_type(8)));
typedef __bf16 bf16x4 __attribute__((ext_vector_type(4)));
typedef float f32x4 __attribute__((ext_vector_type(4)));

#define NROW 3072
#define NF 512            // IN_F == H*D == 512
#define NH 8
#define ND 64

// ---------------------------------------------------------------------------
// Kernel 0: convert the four fp32 tensors to bf16 (vectorized float4 -> bf16x4)
// ---------------------------------------------------------------------------
__global__ __launch_bounds__(256) void k_convert(const float* __restrict__ s0,
                                                 const float* __restrict__ s1,
                                                 const float* __restrict__ s2,
                                                 const float* __restrict__ s3,
                                                 __bf16* __restrict__ d0,
                                                 __bf16* __restrict__ d1,
                                                 __bf16* __restrict__ d2,
                                                 __bf16* __restrict__ d3) {
    const int n0 = NROW * NF / 4, n1 = NF * NF / 4, n2 = NH * ND / 4, n3 = NH * ND / 4;
    int total = n0 + n1 + n2 + n3;
    for (int i = blockIdx.x * 256 + threadIdx.x; i < total; i += gridDim.x * 256) {
        const float4* s; __bf16* d; int k = i;
        if (k < n0)              { s = (const float4*)s0; d = d0; }
        else if ((k -= n0) < n1) { s = (const float4*)s1; d = d1; }
        else if ((k -= n1) < n2) { s = (const float4*)s2; d = d2; }
        else { k -= n2;            s = (const float4*)s3; d = d3; }
        float4 v = s[k];
        bf16x4 o = { (__bf16)v.x, (__bf16)v.y, (__bf16)v.z, (__bf16)v.w };
        *reinterpret_cast<bf16x4*>(d + k * 4) = o;
    }
}

// ---------------------------------------------------------------------------
// Kernel 1: h = x @ W^T (both K-major), write h and hT (per-head d-major).
// ---------------------------------------------------------------------------
__global__ __launch_bounds__(256) void k_gemm_h(const __bf16* __restrict__ x,
                                                const __bf16* __restrict__ W,
                                                __bf16* __restrict__ h,
                                                __bf16* __restrict__ hT) {
    int wave = threadIdx.x >> 6;
    int lane = threadIdx.x & 63;
    int t = blockIdx.x * 4 + wave;          // 6144 tiles: 192 i-tiles x 32 o-tiles
    int i0 = (t >> 5) << 4;
    int o0 = (t & 31) << 4;
    int fr = lane & 15;
    int quad = lane >> 4;

    const bf16x8* xa = reinterpret_cast<const bf16x8*>(x + (i0 + fr) * NF + quad * 8);
    const bf16x8* wb = reinterpret_cast<const bf16x8*>(W + (o0 + fr) * NF + quad * 8);

    f32x4 acc = {0.f, 0.f, 0.f, 0.f};
#pragma unroll
    for (int k = 0; k < 16; ++k) {
        bf16x8 a = xa[k * 4];
        bf16x8 b = wb[k * 4];
        acc = __builtin_amdgcn_mfma_f32_16x16x32_bf16(a, b, acc, 0, 0, 0);
    }
#pragma unroll
    for (int r = 0; r < 4; ++r) {
        int mi = i0 + quad * 4 + r;
        int oo = o0 + fr;
        __bf16 v = (__bf16)acc[r];
        h[mi * NF + oo] = v;
        hT[oo * NROW + mi] = v;
    }
}

// ---------------------------------------------------------------------------
// Kernel 2: e_src[n,h] = <h[n,h,:], a_src[h,:]>, e_dst likewise. fp32 out.
// ---------------------------------------------------------------------------
__global__ __launch_bounds__(64) void k_edges(const __bf16* __restrict__ h,
                                              const __bf16* __restrict__ a_src,
                                              const __bf16* __restrict__ a_dst,
                                              float* __restrict__ e_src,
                                              float* __restrict__ e_dst) {
    int n = blockIdx.x;
    int lane = threadIdx.x;
    bf16x8 hv = *reinterpret_cast<const bf16x8*>(h + n * NF + lane * 8);
    bf16x8 as = *reinterpret_cast<const bf16x8*>(a_src + lane * 8);
    bf16x8 ad = *reinterpret_cast<const bf16x8*>(a_dst + lane * 8);
    float ps = 0.f, pd = 0.f;
#pragma unroll
    for (int t = 0; t < 8; ++t) {
        float hh = (float)hv[t];
        ps += hh * (float)as[t];
        pd += hh * (float)ad[t];
    }
#pragma unroll
    for (int off = 1; off < 8; off <<= 1) {
        ps += __shfl_xor(ps, off, 64);
        pd += __shfl_xor(pd, off, 64);
    }
    if ((lane & 7) == 0) {
        int head = lane >> 3;
        e_src[n * NH + head] = ps;
        e_dst[n * NH + head] = pd;
    }
}

// ---------------------------------------------------------------------------
// Kernel 3: m[i,h] = lrelu(e_src[i,h] + max_{valid j} e_dst[j,h])
// ---------------------------------------------------------------------------
__global__ __launch_bounds__(256) void k_rowmax(const int* __restrict__ adj,
                                                const float* __restrict__ e_src,
                                                const float* __restrict__ e_dst,
                                                float* __restrict__ m_arr) {
    int i = blockIdx.x;
    int tid = threadIdx.x;
    float mx[NH];
#pragma unroll
    for (int hh = 0; hh < NH; ++hh) mx[hh] = -3e38f;

    for (int j = tid; j < NROW; j += 256) {
        int a = adj[i * NROW + j];
        if (a > 0 || j == i) {
            const float4* ep = reinterpret_cast<const float4*>(e_dst + j * NH);
            float4 e0 = ep[0], e1 = ep[1];
            mx[0] = fmaxf(mx[0], e0.x); mx[1] = fmaxf(mx[1], e0.y);
            mx[2] = fmaxf(mx[2], e0.z); mx[3] = fmaxf(mx[3], e0.w);
            mx[4] = fmaxf(mx[4], e1.x); mx[5] = fmaxf(mx[5], e1.y);
            mx[6] = fmaxf(mx[6], e1.z); mx[7] = fmaxf(mx[7], e1.w);
        }
    }
#pragma unroll
    for (int off = 1; off < 64; off <<= 1) {
#pragma unroll
        for (int hh = 0; hh < NH; ++hh) mx[hh] = fmaxf(mx[hh], __shfl_xor(mx[hh], off, 64));
    }
    __shared__ float red[4][NH];
    if ((tid & 63) == 0) {
#pragma unroll
        for (int hh = 0; hh < NH; ++hh) red[tid >> 6][hh] = mx[hh];
    }
    __syncthreads();
    if (tid < NH) {
        float v = fmaxf(fmaxf(red[0][tid], red[1][tid]), fmaxf(red[2][tid], red[3][tid]));
        float e = e_src[i * NH + tid] + v;
        m_arr[i * NH + tid] = e > 0.f ? e : 0.2f * e;
    }
}

// ---------------------------------------------------------------------------
// Kernel 4: flash-style masked softmax-PV, j-split into JCV chunks.
// Grid: 48 i-blocks x JCV j-chunks x 8 heads. Block: 4 waves, each 16 rows.
// Writes disjoint fp32 partials num[jc][i][c], den[jc][i][h] (no init needed).
// ---------------------------------------------------------------------------
template <int JCV>
__global__ __launch_bounds__(256) void k_attn(const int* __restrict__ adj,
                                              const float* __restrict__ e_src,
                                              const float* __restrict__ e_dst,
                                              const float* __restrict__ m_arr,
                                              const __bf16* __restrict__ hT,
                                              float* __restrict__ num,
                                              float* __restrict__ den) {
    constexpr int JCHUNK = NROW / JCV;
    __shared__ float lds_ed[JCHUNK];
    int b = blockIdx.x;
    int head = b & 7;
    int jc = (b >> 3) & (JCV - 1);
    int i0 = (b >> 3) / JCV * 64;
    int jbase = jc * JCHUNK;
    int tid = threadIdx.x;
    int wave = tid >> 6, lane = tid & 63;
    int fr = lane & 15, quad = lane >> 4;

    for (int j = tid; j < JCHUNK; j += 256) lds_ed[j] = e_dst[(jbase + j) * NH + head];
    __syncthreads();

    int irow = i0 + wave * 16 + fr;
    float s_i = e_src[irow * NH + head];
    float m_i = m_arr[irow * NH + head];
    const int* adjrow = adj + irow * NROW + jbase + quad * 8;
    const __bf16* hTh = hT + head * ND * NROW + jbase;

    f32x4 acc0 = {0,0,0,0}, acc1 = {0,0,0,0}, acc2 = {0,0,0,0}, acc3 = {0,0,0,0};
    float lsum = 0.f;

    for (int j0 = 0; j0 < JCHUNK; j0 += 32) {
        int4 a0 = *reinterpret_cast<const int4*>(adjrow + j0);
        int4 a1 = *reinterpret_cast<const int4*>(adjrow + j0 + 4);
        int av[8] = {a0.x, a0.y, a0.z, a0.w, a1.x, a1.y, a1.z, a1.w};
        bf16x8 af;
#pragma unroll
        for (int t = 0; t < 8; ++t) {
            int j = j0 + quad * 8 + t;
            float e = s_i + lds_ed[j];
            e = e > 0.f ? e : 0.2f * e;
            float p = (av[t] > 0 || (jbase + j) == irow) ? __expf(fminf(e - m_i, 0.f)) : 0.f;
            af[t] = (__bf16)p;
            lsum += (float)af[t];          // denominator consistent with bf16 P
        }
        const __bf16* vb = hTh + fr * NROW + j0 + quad * 8;
        acc0 = __builtin_amdgcn_mfma_f32_16x16x32_bf16(af, *reinterpret_cast<const bf16x8*>(vb),             acc0, 0, 0, 0);
        acc1 = __builtin_amdgcn_mfma_f32_16x16x32_bf16(af, *reinterpret_cast<const bf16x8*>(vb + 16 * NROW), acc1, 0, 0, 0);
        acc2 = __builtin_amdgcn_mfma_f32_16x16x32_bf16(af, *reinterpret_cast<const bf16x8*>(vb + 32 * NROW), acc2, 0, 0, 0);
        acc3 = __builtin_amdgcn_mfma_f32_16x16x32_bf16(af, *reinterpret_cast<const bf16x8*>(vb + 48 * NROW), acc3, 0, 0, 0);
    }

    lsum += __shfl_xor(lsum, 16, 64);
    lsum += __shfl_xor(lsum, 32, 64);    // lane L holds total for row (L&15)

    if (quad == 0)
        den[(jc * NROW + i0 + wave * 16 + fr) * NH + head] = lsum;

#pragma unroll
    for (int r = 0; r < 4; ++r) {
        int orow = quad * 4 + r;
        int ob = (jc * NROW + i0 + wave * 16 + orow) * NF + head * ND + fr;
        num[ob +  0] = acc0[r];
        num[ob + 16] = acc1[r];
        num[ob + 32] = acc2[r];
        num[ob + 48] = acc3[r];
    }
}

// ---------------------------------------------------------------------------
// Kernel 5: out[i,c] = sum_jc num[jc][i][c] / sum_jc den[jc][i][c>>6]
// ---------------------------------------------------------------------------
__global__ __launch_bounds__(256) void k_reduce(const float* __restrict__ num,
                                                const float* __restrict__ den,
                                                float* __restrict__ out, int jcv) {
    int idx = blockIdx.x * 256 + threadIdx.x;     // 0 .. NROW*NF
    int i = idx >> 9;
    int c = idx & 511;
    int head = c >> 6;
    float ns = 0.f, ds = 0.f;
    for (int k = 0; k < jcv; ++k) {
        ns += num[(k * NROW + i) * NF + c];
        ds += den[(k * NROW + i) * NH + head];
    }
    out[idx] = ns / fmaxf(ds, 1e-30f);
}

// ---------------------------------------------------------------------------
extern "C" void kernel_launch(void* const* d_in, const int* in_sizes, int n_in,
                              void* d_out, int out_size, void* d_ws, size_t ws_size,
                              hipStream_t stream) {
    const float* x_raw  = (const float*)d_in[0];
    const int*   adj    = (const int*)d_in[1];
    const float* W_raw  = (const float*)d_in[2];
    const float* as_raw = (const float*)d_in[3];
    const float* ad_raw = (const float*)d_in[4];
    float* out = (float*)d_out;

    char* ws = (char*)d_ws;
    __bf16* h      = (__bf16*)(ws);                      // 3,145,728 B
    __bf16* hT     = (__bf16*)(ws + 3145728);            // 3,145,728 B
    float*  e_src  = (float*)(ws + 6291456);             //    98,304 B
    float*  e_dst  = (float*)(ws + 6389760);             //    98,304 B
    float*  m_arr  = (float*)(ws + 6488064);             //    98,304 B
    __bf16* xb     = (__bf16*)(ws + 6586368);            // 3,145,728 B
    __bf16* Wb     = (__bf16*)(ws + 9732096);            //   524,288 B
    __bf16* a_srcb = (__bf16*)(ws + 10256384);           //     1,024 B
    __bf16* a_dstb = (__bf16*)(ws + 10257408);           //     1,024 B
    float*  num    = (float*)(ws + 10258432);            // JC*6,291,456 B
    // den follows num; size depends on JC

    // JC=4 needs 10258432 + 4*6291456 + 4*98304 = 35,817,472 B of ws
    int jcv = (ws_size >= 36000000u) ? 4 : 1;
    float* den = (float*)(ws + 10258432 + (size_t)jcv * 6291456);

    k_convert<<<1024, 256, 0, stream>>>(x_raw, W_raw, as_raw, ad_raw,
                                        xb, Wb, a_srcb, a_dstb);
    k_gemm_h<<<1536, 256, 0, stream>>>(xb, Wb, h, hT);
    k_edges<<<NROW, 64, 0, stream>>>(h, a_srcb, a_dstb, e_src, e_dst);
    k_rowmax<<<NROW, 256, 0, stream>>>(adj, e_src, e_dst, m_arr);
    if (jcv == 4)
        k_attn<4><<<48 * 4 * 8, 256, 0, stream>>>(adj, e_src, e_dst, m_arr, hT, num, den);
    else
        k_attn<1><<<48 * 1 * 8, 256, 0, stream>>>(adj, e_src, e_dst, m_arr, hT, num, den);
    k_reduce<<<NROW * NF / 256, 256, 0, stream>>>(num, den, out, jcv);
}

// Round 4
// 226.680 us; speedup vs baseline: 1.2964x; 1.0632x over previous
//
#include <hip/hip_runtime.h>
#include <hip/hip_bf16.h>

typedef __bf16 bf16x8 __attribute__((ext_vector_type(8)));
typedef __bf16 bf16x4 __attribute__((ext_vector_type(4)));
typedef float f32x4 __attribute__((ext_vector_type(4)));

#define NROW 3072
#define NF 512            // IN_F == H*D == 512
#define NH 8
#define ND 64

// ---------------------------------------------------------------------------
// Kernel 0: convert the four fp32 tensors to bf16 (vectorized float4 -> bf16x4)
// ---------------------------------------------------------------------------
__global__ __launch_bounds__(256) void k_convert(const float* __restrict__ s0,
                                                 const float* __restrict__ s1,
                                                 const float* __restrict__ s2,
                                                 const float* __restrict__ s3,
                                                 __bf16* __restrict__ d0,
                                                 __bf16* __restrict__ d1,
                                                 __bf16* __restrict__ d2,
                                                 __bf16* __restrict__ d3) {
    const int n0 = NROW * NF / 4, n1 = NF * NF / 4, n2 = NH * ND / 4, n3 = NH * ND / 4;
    int total = n0 + n1 + n2 + n3;
    for (int i = blockIdx.x * 256 + threadIdx.x; i < total; i += gridDim.x * 256) {
        const float4* s; __bf16* d; int k = i;
        if (k < n0)              { s = (const float4*)s0; d = d0; }
        else if ((k -= n0) < n1) { s = (const float4*)s1; d = d1; }
        else if ((k -= n1) < n2) { s = (const float4*)s2; d = d2; }
        else { k -= n2;            s = (const float4*)s3; d = d3; }
        float4 v = s[k];
        bf16x4 o = { (__bf16)v.x, (__bf16)v.y, (__bf16)v.z, (__bf16)v.w };
        *reinterpret_cast<bf16x4*>(d + k * 4) = o;
    }
}

// ---------------------------------------------------------------------------
// Kernel 1: h = x @ W^T (both K-major), write h and hT (per-head d-major).
// ---------------------------------------------------------------------------
__global__ __launch_bounds__(256) void k_gemm_h(const __bf16* __restrict__ x,
                                                const __bf16* __restrict__ W,
                                                __bf16* __restrict__ h,
                                                __bf16* __restrict__ hT) {
    int wave = threadIdx.x >> 6;
    int lane = threadIdx.x & 63;
    int t = blockIdx.x * 4 + wave;          // 6144 tiles: 192 i-tiles x 32 o-tiles
    int i0 = (t >> 5) << 4;
    int o0 = (t & 31) << 4;
    int fr = lane & 15;
    int quad = lane >> 4;

    const bf16x8* xa = reinterpret_cast<const bf16x8*>(x + (i0 + fr) * NF + quad * 8);
    const bf16x8* wb = reinterpret_cast<const bf16x8*>(W + (o0 + fr) * NF + quad * 8);

    f32x4 acc = {0.f, 0.f, 0.f, 0.f};
#pragma unroll
    for (int k = 0; k < 16; ++k) {
        bf16x8 a = xa[k * 4];
        bf16x8 b = wb[k * 4];
        acc = __builtin_amdgcn_mfma_f32_16x16x32_bf16(a, b, acc, 0, 0, 0);
    }
#pragma unroll
    for (int r = 0; r < 4; ++r) {
        int mi = i0 + quad * 4 + r;
        int oo = o0 + fr;
        __bf16 v = (__bf16)acc[r];
        h[mi * NF + oo] = v;
        hT[oo * NROW + mi] = v;
    }
}

// ---------------------------------------------------------------------------
// Kernel 2: e_src[n,h] = <h[n,h,:], a_src[h,:]>, e_dst likewise. fp32 out.
// ---------------------------------------------------------------------------
__global__ __launch_bounds__(64) void k_edges(const __bf16* __restrict__ h,
                                              const __bf16* __restrict__ a_src,
                                              const __bf16* __restrict__ a_dst,
                                              float* __restrict__ e_src,
                                              float* __restrict__ e_dst) {
    int n = blockIdx.x;
    int lane = threadIdx.x;
    bf16x8 hv = *reinterpret_cast<const bf16x8*>(h + n * NF + lane * 8);
    bf16x8 as = *reinterpret_cast<const bf16x8*>(a_src + lane * 8);
    bf16x8 ad = *reinterpret_cast<const bf16x8*>(a_dst + lane * 8);
    float ps = 0.f, pd = 0.f;
#pragma unroll
    for (int t = 0; t < 8; ++t) {
        float hh = (float)hv[t];
        ps += hh * (float)as[t];
        pd += hh * (float)ad[t];
    }
#pragma unroll
    for (int off = 1; off < 8; off <<= 1) {
        ps += __shfl_xor(ps, off, 64);
        pd += __shfl_xor(pd, off, 64);
    }
    if ((lane & 7) == 0) {
        int head = lane >> 3;
        e_src[n * NH + head] = ps;
        e_dst[n * NH + head] = pd;
    }
}

// ---------------------------------------------------------------------------
// Kernel 3: colmax[h] = max_j e_dst[j,h]  (global, softmax shift is free)
// ---------------------------------------------------------------------------
__global__ __launch_bounds__(64) void k_colmax(const float* __restrict__ e_dst,
                                               float* __restrict__ colmax) {
    int head = blockIdx.x;
    int lane = threadIdx.x;
    float mx = -3e38f;
    for (int j = lane; j < NROW; j += 64) mx = fmaxf(mx, e_dst[j * NH + head]);
#pragma unroll
    for (int off = 1; off < 64; off <<= 1) mx = fmaxf(mx, __shfl_xor(mx, off, 64));
    if (lane == 0) colmax[head] = mx;
}

// ---------------------------------------------------------------------------
// Kernel 4: masked softmax-PV with factored exp.
//   m'_i = lrelu(s_i + Mg);  p_ij = mask * (P_j>T_i ? A_i*P_j : C_i*Q_j)
//   A_i = e^{min(u,0)*0.8}, C_i = e^{-max(u,0)*0.8}, T_i = e^{-u}, u = s_i+Mg
//   P_j = e^{d_j-Mg}, Q_j = e^{0.2(d_j-Mg)}  (preloaded to LDS once per block)
// Grid: 48 i-blocks x JCV j-chunks x 8 heads; 4 waves; 16 rows/wave.
// Software-prefetched adj + hT; LDS reads via ds_read_b128.
// ---------------------------------------------------------------------------
template <int JCV>
__global__ __launch_bounds__(256) void k_attn(const int* __restrict__ adj,
                                              const float* __restrict__ e_src,
                                              const float* __restrict__ e_dst,
                                              const float* __restrict__ colmax,
                                              const __bf16* __restrict__ hT,
                                              float* __restrict__ num,
                                              float* __restrict__ den) {
    constexpr int JCHUNK = NROW / JCV;
    __shared__ __align__(16) float2 lds_pq[JCHUNK];
    int b = blockIdx.x;
    int head = b & 7;
    int jc = (b >> 3) & (JCV - 1);
    int i0 = (b >> 3) / JCV * 64;
    int jbase = jc * JCHUNK;
    int tid = threadIdx.x;
    int wave = tid >> 6, lane = tid & 63;
    int fr = lane & 15, quad = lane >> 4;

    float Mg = colmax[head];
    for (int j = tid; j < JCHUNK; j += 256) {
        float t = e_dst[(jbase + j) * NH + head] - Mg;   // <= 0
        lds_pq[j] = make_float2(__expf(t), __expf(0.2f * t));
    }
    __syncthreads();

    int irow = i0 + wave * 16 + fr;
    float s = e_src[irow * NH + head];
    float u = s + Mg;
    float A = (u > 0.f) ? 1.f : __expf(0.8f * u);
    float C = (u > 0.f) ? __expf(-0.8f * u) : 1.f;
    float T = __expf(-u);
    int selfj = irow - jbase - quad * 8;     // in-chunk self index, quad-shifted

    const int* adjrow = adj + irow * NROW + jbase + quad * 8;
    const __bf16* hTh = hT + (head * ND + fr) * NROW + jbase + quad * 8;

    f32x4 acc0 = {0,0,0,0}, acc1 = {0,0,0,0}, acc2 = {0,0,0,0}, acc3 = {0,0,0,0};
    float lsum = 0.f;

    // software pipeline: preload tile 0
    int4 a0 = *reinterpret_cast<const int4*>(adjrow);
    int4 a1 = *reinterpret_cast<const int4*>(adjrow + 4);
    bf16x8 v0 = *reinterpret_cast<const bf16x8*>(hTh);
    bf16x8 v1 = *reinterpret_cast<const bf16x8*>(hTh + 16 * NROW);
    bf16x8 v2 = *reinterpret_cast<const bf16x8*>(hTh + 32 * NROW);
    bf16x8 v3 = *reinterpret_cast<const bf16x8*>(hTh + 48 * NROW);

    for (int j0 = 0; j0 < JCHUNK; j0 += 32) {
        // prefetch next tile (clamped address; last-iter fetch is discarded)
        int jn = (j0 + 32 < JCHUNK) ? (j0 + 32) : 0;
        int4 na0 = *reinterpret_cast<const int4*>(adjrow + jn);
        int4 na1 = *reinterpret_cast<const int4*>(adjrow + jn + 4);
        bf16x8 nv0 = *reinterpret_cast<const bf16x8*>(hTh + jn);
        bf16x8 nv1 = *reinterpret_cast<const bf16x8*>(hTh + jn + 16 * NROW);
        bf16x8 nv2 = *reinterpret_cast<const bf16x8*>(hTh + jn + 32 * NROW);
        bf16x8 nv3 = *reinterpret_cast<const bf16x8*>(hTh + jn + 48 * NROW);

        // 8 (P,Q) pairs = 4x ds_read_b128 (quad-broadcast, conflict-free)
        const float4* lp = reinterpret_cast<const float4*>(&lds_pq[j0 + quad * 8]);
        float4 q01 = lp[0], q23 = lp[1], q45 = lp[2], q67 = lp[3];
        float P[8] = {q01.x, q01.z, q23.x, q23.z, q45.x, q45.z, q67.x, q67.z};
        float Q[8] = {q01.y, q01.w, q23.y, q23.w, q45.y, q45.w, q67.y, q67.w};
        int av[8] = {a0.x, a0.y, a0.z, a0.w, a1.x, a1.y, a1.z, a1.w};

        bf16x8 af;
#pragma unroll
        for (int t = 0; t < 8; ++t) {
            bool pos = P[t] > T;
            float p = (pos ? P[t] : Q[t]) * (pos ? A : C);
            bool valid = (av[t] > 0) || (j0 + t == selfj);
            p = valid ? p : 0.f;
            af[t] = (__bf16)p;
            lsum += (float)af[t];          // denominator consistent with bf16 P
        }
        acc0 = __builtin_amdgcn_mfma_f32_16x16x32_bf16(af, v0, acc0, 0, 0, 0);
        acc1 = __builtin_amdgcn_mfma_f32_16x16x32_bf16(af, v1, acc1, 0, 0, 0);
        acc2 = __builtin_amdgcn_mfma_f32_16x16x32_bf16(af, v2, acc2, 0, 0, 0);
        acc3 = __builtin_amdgcn_mfma_f32_16x16x32_bf16(af, v3, acc3, 0, 0, 0);
        a0 = na0; a1 = na1; v0 = nv0; v1 = nv1; v2 = nv2; v3 = nv3;
    }

    lsum += __shfl_xor(lsum, 16, 64);
    lsum += __shfl_xor(lsum, 32, 64);    // lane L holds total for row (L&15)

    if (quad == 0)
        den[(jc * NROW + i0 + wave * 16 + fr) * NH + head] = lsum;

#pragma unroll
    for (int r = 0; r < 4; ++r) {
        int orow = quad * 4 + r;
        int ob = (jc * NROW + i0 + wave * 16 + orow) * NF + head * ND + fr;
        num[ob +  0] = acc0[r];
        num[ob + 16] = acc1[r];
        num[ob + 32] = acc2[r];
        num[ob + 48] = acc3[r];
    }
}

// ---------------------------------------------------------------------------
// Kernel 5: out[i,c] = sum_jc num[jc][i][c] / sum_jc den[jc][i][c>>6]
// ---------------------------------------------------------------------------
__global__ __launch_bounds__(256) void k_reduce(const float* __restrict__ num,
                                                const float* __restrict__ den,
                                                float* __restrict__ out, int jcv) {
    int idx = blockIdx.x * 256 + threadIdx.x;     // 0 .. NROW*NF
    int i = idx >> 9;
    int c = idx & 511;
    int head = c >> 6;
    float ns = 0.f, ds = 0.f;
    for (int k = 0; k < jcv; ++k) {
        ns += num[(k * NROW + i) * NF + c];
        ds += den[(k * NROW + i) * NH + head];
    }
    out[idx] = ns / fmaxf(ds, 1e-30f);
}

// ---------------------------------------------------------------------------
extern "C" void kernel_launch(void* const* d_in, const int* in_sizes, int n_in,
                              void* d_out, int out_size, void* d_ws, size_t ws_size,
                              hipStream_t stream) {
    const float* x_raw  = (const float*)d_in[0];
    const int*   adj    = (const int*)d_in[1];
    const float* W_raw  = (const float*)d_in[2];
    const float* as_raw = (const float*)d_in[3];
    const float* ad_raw = (const float*)d_in[4];
    float* out = (float*)d_out;

    char* ws = (char*)d_ws;
    __bf16* h      = (__bf16*)(ws);                      // 3,145,728 B
    __bf16* hT     = (__bf16*)(ws + 3145728);            // 3,145,728 B
    float*  e_src  = (float*)(ws + 6291456);             //    98,304 B
    float*  e_dst  = (float*)(ws + 6389760);             //    98,304 B
    float*  cmax   = (float*)(ws + 6488064);             //     1,024 B
    __bf16* xb     = (__bf16*)(ws + 6489088);            // 3,145,728 B
    __bf16* Wb     = (__bf16*)(ws + 9634816);            //   524,288 B
    __bf16* a_srcb = (__bf16*)(ws + 10159104);           //     1,024 B
    __bf16* a_dstb = (__bf16*)(ws + 10160128);           //     1,024 B
    float*  num    = (float*)(ws + 10161152);            // JC*6,291,456 B
    // den follows num

    // JC=4 needs 10161152 + 4*6291456 + 4*98304 = 35,720,192 B
    int jcv = (ws_size >= 35800000u) ? 4 : 1;
    float* den = (float*)(ws + 10161152 + (size_t)jcv * 6291456);

    k_convert<<<1024, 256, 0, stream>>>(x_raw, W_raw, as_raw, ad_raw,
                                        xb, Wb, a_srcb, a_dstb);
    k_gemm_h<<<1536, 256, 0, stream>>>(xb, Wb, h, hT);
    k_edges<<<NROW, 64, 0, stream>>>(h, a_srcb, a_dstb, e_src, e_dst);
    k_colmax<<<NH, 64, 0, stream>>>(e_dst, cmax);
    if (jcv == 4)
        k_attn<4><<<48 * 4 * 8, 256, 0, stream>>>(adj, e_src, e_dst, cmax, hT, num, den);
    else
        k_attn<1><<<48 * 1 * 8, 256, 0, stream>>>(adj, e_src, e_dst, cmax, hT, num, den);
    k_reduce<<<NROW * NF / 256, 256, 0, stream>>>(num, den, out, jcv);
}